// Round 2
// baseline (603.062 us; speedup 1.0000x reference)
//
#include <hip/hip_runtime.h>
#include <cstdint>

#define B_  64
#define P_  196
#define C_  768
#define HS_ 384

// fc1 GEMM: M=B_*C_ (r=b*768+c), N=384, K=1792 (0..1567 rbf | 1568..1763 silu | pad)
// fc2 GEMM: M=B_*C_, N=208 (196 live), K=3456 (0..3071 rbf | 3072..3455 silu)
#define KT1 56
#define NT1 24
#define KT2 108
#define NT2 13

#define H1_ELEMS  (B_*C_*HS_)       // 18,874,368 bf16
#define W1P_ELEMS (KT1*NT1*64*8)    // 688,128
#define W2P_ELEMS (KT2*NT2*64*8)    // 718,848

typedef __attribute__((ext_vector_type(8))) short short8;
typedef __attribute__((ext_vector_type(4))) float f32x4;

static __device__ __forceinline__ float bf2f(unsigned short u) {
    union { unsigned int i; float f; } v; v.i = ((unsigned int)u) << 16; return v.f;
}
static __device__ __forceinline__ unsigned short f2bf(float f) {
    union { float f; unsigned int i; } v; v.f = f;
    unsigned int r = v.i + 0x7FFFu + ((v.i >> 16) & 1u);
    return (unsigned short)(r >> 16);
}

// Pack fp32 weights into bf16 MFMA B-fragment wave order:
// pack[t][nt][lane][j] = W[n = nt*16 + (lane&15)][k = t*32 + (lane>>4)*8 + j]
// where W = [spline_w | base_w | zero-pad] along k (and zero rows for n-pad in fc2).
__global__ void pack_w_kernel(const float* __restrict__ w1s,
                              const float* __restrict__ w1b,
                              const float* __restrict__ w2s,
                              const float* __restrict__ w2b,
                              unsigned short* __restrict__ w1p,
                              unsigned short* __restrict__ w2p) {
    int idx = blockIdx.x * 256 + threadIdx.x;
    if (idx < W1P_ELEMS) {
        int j    = idx & 7;
        int lane = (idx >> 3) & 63;
        int g    = idx >> 9;            // t*NT1 + nt
        int nt   = g % NT1;
        int t    = g / NT1;
        int n = nt*16 + (lane & 15);
        int k = t*32 + (lane >> 4)*8 + j;
        float v = 0.f;
        if (k < 1568)      v = w1s[n*1568 + k];
        else if (k < 1764) v = w1b[n*196 + (k - 1568)];
        w1p[idx] = f2bf(v);
    } else {
        int idx2 = idx - W1P_ELEMS;
        if (idx2 < W2P_ELEMS) {
            int j    = idx2 & 7;
            int lane = (idx2 >> 3) & 63;
            int g    = idx2 >> 9;       // t*NT2 + nt
            int nt   = g % NT2;
            int t    = g / NT2;
            int n = nt*16 + (lane & 15);
            int k = t*32 + (lane >> 4)*8 + j;
            float v = 0.f;
            if (n < 196) {
                if (k < 3072) v = w2s[n*3072 + k];
                else          v = w2b[n*384 + (k - 3072)];
            }
            w2p[idx2] = f2bf(v);
        }
    }
}

// rbf fragment: 8 values exp(-((s-g_j)*3.5)^2), g_j = -1 + j*(2/7)
// => d_j = 3.5*s + 3.5 - j
static __device__ __forceinline__ short8 rbf_frag(float s) {
    short8 f;
    float t0 = 3.5f * s + 3.5f;
#pragma unroll
    for (int j = 0; j < 8; j++) {
        float d = t0 - (float)j;
        f[j] = (short)f2bf(__expf(-d * d));
    }
    return f;
}

#define XS_STRIDE 226   // floats; 226 mod 32 = 2 -> 2-way LDS aliasing (free)

__global__ __launch_bounds__(256, 2)
void fc1_kernel(const float* __restrict__ x,
                const unsigned short* __restrict__ w1p,
                const float* __restrict__ b1,
                unsigned short* __restrict__ h1) {
    __shared__ float xs[64 * XS_STRIDE];   // 57.9 KB
    int blk = blockIdx.x;
    int b   = blk / 12;
    int c0  = (blk % 12) * 64;
    int tid = threadIdx.x;

    // stage x transposed: xs[c][p] = x[b, p, c0+c]
    for (int i = tid; i < 196 * 64; i += 256) {
        int p = i >> 6, c = i & 63;
        xs[c * XS_STRIDE + p] = x[(b * P_ + p) * C_ + c0 + c];
    }
    for (int i = tid; i < 64 * 28; i += 256) {   // zero pad p = 196..223
        int c = i / 28, p = 196 + (i % 28);
        xs[c * XS_STRIDE + p] = 0.f;
    }
    __syncthreads();

    int wave = tid >> 6, lane = tid & 63;
    int m = lane & 15, quad = lane >> 4;
    const float* xrow = &xs[(wave * 16 + m) * XS_STRIDE];

    f32x4 acc[NT1];
#pragma unroll
    for (int i = 0; i < NT1; i++) acc[i] = (f32x4){0.f, 0.f, 0.f, 0.f};

    const short8* wp = (const short8*)w1p;
    for (int t = 0; t < KT1; t++) {
        short8 afrag;
        if (t < 49) {                       // rbf region: one scalar -> 8 basis values
            afrag = rbf_frag(xrow[t * 4 + quad]);
        } else {                            // silu region (+ zero pad rows)
            int pb = (t - 49) * 32 + quad * 8;
#pragma unroll
            for (int j = 0; j < 8; j++) {
                float s = xrow[pb + j];
                afrag[j] = (short)f2bf(s / (1.f + __expf(-s)));
            }
        }
        const short8* wt = wp + (size_t)(t * NT1) * 64 + lane;
#pragma unroll
        for (int nt = 0; nt < NT1; nt++) {
            short8 bfrag = wt[nt * 64];
            acc[nt] = __builtin_amdgcn_mfma_f32_16x16x32_bf16(afrag, bfrag, acc[nt], 0, 0, 0);
        }
    }

    // epilogue: h1[r][n] = acc + bias1[n]  (C/D: col=lane&15, row=quad*4+reg)
    int r0 = blk * 64 + wave * 16 + quad * 4;
#pragma unroll
    for (int nt = 0; nt < NT1; nt++) {
        int n = nt * 16 + m;
        float bv = b1[n];
#pragma unroll
        for (int rg = 0; rg < 4; rg++) {
            h1[(size_t)(r0 + rg) * HS_ + n] = f2bf(acc[nt][rg] + bv);
        }
    }
}

#define HS_STRIDE 392   // ushorts; 784 B row stride, 16B-aligned

__global__ __launch_bounds__(256, 2)
void fc2_kernel(const unsigned short* __restrict__ h1,
                const unsigned short* __restrict__ w2p,
                const float* __restrict__ b2,
                const float* __restrict__ x,
                float* __restrict__ out) {
    __shared__ unsigned short hs[64 * HS_STRIDE];   // 49 KB
    int blk = blockIdx.x;
    int r0b = blk * 64;
    int tid = threadIdx.x;

    // stage h1 rows r0b..r0b+63 (row-major bf16, vectorized 16B)
    const uint4* h4 = (const uint4*)(h1 + (size_t)r0b * HS_);
    for (int i = tid; i < 64 * 48; i += 256) {
        int r = i / 48, q = i % 48;
        *(uint4*)&hs[r * HS_STRIDE + q * 8] = h4[i];
    }
    __syncthreads();

    int wave = tid >> 6, lane = tid & 63;
    int m = lane & 15, quad = lane >> 4;
    const unsigned short* hrow = &hs[(wave * 16 + m) * HS_STRIDE];

    f32x4 acc[NT2];
#pragma unroll
    for (int i = 0; i < NT2; i++) acc[i] = (f32x4){0.f, 0.f, 0.f, 0.f};

    const short8* wp = (const short8*)w2p;
    for (int t = 0; t < KT2; t++) {
        short8 afrag;
        if (t < 96) {                       // rbf over h1
            afrag = rbf_frag(bf2f(hrow[t * 4 + quad]));
        } else {                            // silu over h1 (k = 3072..3455 -> q = 0..383)
            int pb = (t - 96) * 32 + quad * 8;
#pragma unroll
            for (int j = 0; j < 8; j++) {
                float s = bf2f(hrow[pb + j]);
                afrag[j] = (short)f2bf(s / (1.f + __expf(-s)));
            }
        }
        const short8* wt = wp + (size_t)(t * NT2) * 64 + lane;
#pragma unroll
        for (int nt = 0; nt < NT2; nt++) {
            short8 bfrag = wt[nt * 64];
            acc[nt] = __builtin_amdgcn_mfma_f32_16x16x32_bf16(afrag, bfrag, acc[nt], 0, 0, 0);
        }
    }

    // epilogue: out[b, p, c] = acc + bias2[p] + x[b, p, c]  (fp32, exact skip path)
    int b     = r0b / C_;
    int cbase = (r0b % C_) + wave * 16 + quad * 4;   // 4 consecutive c via reg idx
#pragma unroll
    for (int nt = 0; nt < NT2; nt++) {
        int p = nt * 16 + m;
        if (p < 196) {
            float bv = b2[p];
            size_t off = (size_t)(b * P_ + p) * C_ + cbase;
            float4 xv = *(const float4*)(x + off);
            float4 ov;
            ov.x = acc[nt][0] + bv + xv.x;
            ov.y = acc[nt][1] + bv + xv.y;
            ov.z = acc[nt][2] + bv + xv.z;
            ov.w = acc[nt][3] + bv + xv.w;
            *(float4*)(out + off) = ov;
        }
    }
}

extern "C" void kernel_launch(void* const* d_in, const int* in_sizes, int n_in,
                              void* d_out, int out_size, void* d_ws, size_t ws_size,
                              hipStream_t stream) {
    const float* x   = (const float*)d_in[0];
    const float* w1s = (const float*)d_in[1];
    const float* w1b = (const float*)d_in[2];
    const float* b1  = (const float*)d_in[3];
    const float* w2s = (const float*)d_in[4];
    const float* w2b = (const float*)d_in[5];
    const float* b2  = (const float*)d_in[6];
    float* out = (float*)d_out;

    unsigned short* h1  = (unsigned short*)d_ws;            // 37.75 MB bf16
    unsigned short* w1p = h1 + H1_ELEMS;                    // 1.31 MB
    unsigned short* w2p = w1p + W1P_ELEMS;                  // 1.37 MB  (total ~40.6 MB)

    pack_w_kernel<<<(W1P_ELEMS + W2P_ELEMS) / 256, 256, 0, stream>>>(w1s, w1b, w2s, w2b, w1p, w2p);
    fc1_kernel<<<(B_ * C_) / 64, 256, 0, stream>>>(x, w1p, b1, h1);
    fc2_kernel<<<(B_ * C_) / 64, 256, 0, stream>>>(h1, w2p, b2, x, out);
}

// Round 3
// 530.652 us; speedup vs baseline: 1.1365x; 1.1365x over previous
//
#include <hip/hip_runtime.h>
#include <cstdint>

#define B_  64
#define P_  196
#define C_  768
#define HS_ 384
#define M_  (B_*C_)   // 49152 rows

// fc1 GEMM (32x32x16): M=49152, N=384 (12 nt), K=1792 = 98 rbf-kt + 14 silu-kt
// fc2 GEMM (32x32x16): M=49152, N=224 (7 nt, 196 live), K=3456 = 192 rbf-kt + 24 silu-kt
#define KT1 112
#define NT1 12
#define KT2 216
#define NT2 7

#define H1_ELEMS  (M_*HS_)          // 18,874,368 bf16 (stored transposed: h1t[n][r])
#define W1P_ELEMS (KT1*NT1*512)     // 688,128
#define W2P_ELEMS (KT2*NT2*512)     // 774,144

typedef __attribute__((ext_vector_type(8)))  short short8;
typedef __attribute__((ext_vector_type(16))) float f32x16;

static __device__ __forceinline__ float bf2f(unsigned short u) {
    union { unsigned int i; float f; } v; v.i = ((unsigned int)u) << 16; return v.f;
}
static __device__ __forceinline__ unsigned short f2bf_rne(float f) {
    union { float f; unsigned int i; } v; v.f = f;
    unsigned int r = v.i + 0x7FFFu + ((v.i >> 16) & 1u);
    return (unsigned short)(r >> 16);
}

// pack two fp32 -> bf16 pair (round-to-nearest via +0x8000, then v_perm byte-select)
static __device__ __forceinline__ unsigned int pack2(float a, float b) {
    unsigned int ua = __float_as_uint(a) + 0x8000u;
    unsigned int ub = __float_as_uint(b) + 0x8000u;
    return __builtin_amdgcn_perm(ub, ua, 0x07060302u);  // [a.hi16 | b.hi16]
}

// 8 RBF basis values of one scalar: exp(-((s-g_j)*3.5)^2), g_j = -1 + j*2/7
static __device__ __forceinline__ short8 rbf8(float s) {
    float t0 = 3.5f * s + 3.5f;           // d_j = t0 - j
    union { short8 s8; unsigned int u[4]; } r;
#pragma unroll
    for (int q = 0; q < 4; q++) {
        float d0 = t0 - (float)(2 * q);
        float d1 = t0 - (float)(2 * q + 1);
        float e0 = __expf(-d0 * d0);
        float e1 = __expf(-d1 * d1);
        r.u[q] = pack2(e0, e1);
    }
    return r.s8;
}

static __device__ __forceinline__ short8 silu8(const float* v) {
    union { short8 s8; unsigned int u[4]; } r;
#pragma unroll
    for (int q = 0; q < 4; q++) {
        float s0 = v[2 * q], s1 = v[2 * q + 1];
        float f0 = s0 * __builtin_amdgcn_rcpf(1.f + __expf(-s0));
        float f1 = s1 * __builtin_amdgcn_rcpf(1.f + __expf(-s1));
        r.u[q] = pack2(f0, f1);
    }
    return r.s8;
}

// Weights packed as MFMA A-operand fragments (lane&31 = n, (lane>>5)*8+j = k):
// pack[t][nt][lane][j] = W[n = nt*32 + (lane&31)][k = t*16 + (lane>>5)*8 + j]
__global__ void pack_w_kernel(const float* __restrict__ w1s,
                              const float* __restrict__ w1b,
                              const float* __restrict__ w2s,
                              const float* __restrict__ w2b,
                              unsigned short* __restrict__ w1p,
                              unsigned short* __restrict__ w2p) {
    int idx = blockIdx.x * 256 + threadIdx.x;
    if (idx < W1P_ELEMS) {
        int j    = idx & 7;
        int lane = (idx >> 3) & 63;
        int g    = idx >> 9;            // t*NT1 + nt
        int nt   = g % NT1;
        int t    = g / NT1;
        int n = nt * 32 + (lane & 31);
        int k = t * 16 + (lane >> 5) * 8 + j;
        float v = 0.f;
        if (k < 1568)      v = w1s[n * 1568 + k];
        else if (k < 1764) v = w1b[n * 196 + (k - 1568)];
        w1p[idx] = f2bf_rne(v);
    } else {
        int idx2 = idx - W1P_ELEMS;
        if (idx2 < W2P_ELEMS) {
            int j    = idx2 & 7;
            int lane = (idx2 >> 3) & 63;
            int g    = idx2 >> 9;       // t*NT2 + nt
            int nt   = g % NT2;
            int t    = g / NT2;
            int n = nt * 32 + (lane & 31);
            int k = t * 16 + (lane >> 5) * 8 + j;
            float v = 0.f;
            if (n < 196) {
                if (k < 3072) v = w2s[n * 3072 + k];
                else          v = w2b[n * 384 + (k - 3072)];
            }
            w2p[idx2] = f2bf_rne(v);
        }
    }
}

// fc1: D[n][r] = W1 * act(x)^T; writes h1t[n][r] (transposed), fully coalesced.
// block = 4 waves = 2 r-groups x 2 n-groups, covers 128 rows; no LDS, no syncs.
__global__ __launch_bounds__(256, 2)
void fc1_kernel(const float* __restrict__ x,
                const unsigned short* __restrict__ w1p,
                const float* __restrict__ b1,
                unsigned short* __restrict__ h1t) {
    int blk = blockIdx.x;
    int b   = blk / 6;
    int c0  = (blk % 6) * 128;
    int tid  = threadIdx.x;
    int wave = tid >> 6, lane = tid & 63;
    int rg = wave >> 1, ng = wave & 1;
    int half = lane >> 5, l31 = lane & 31;
    const float* xb = x + (size_t)b * (P_ * C_);
    int cb0 = c0 + rg * 64 + l31;        // + rt*32

    f32x16 acc[2][6];
#pragma unroll
    for (int rt = 0; rt < 2; rt++)
#pragma unroll
        for (int nt = 0; nt < 6; nt++)
#pragma unroll
            for (int i = 0; i < 16; i++) acc[rt][nt][i] = 0.f;

    const short8* wp = (const short8*)w1p;
    for (int t = 0; t < KT1; t++) {
        short8 act[2];
        if (t < 98) {                    // rbf: scalar p = 2t+half, coalesced 128B
            int p = 2 * t + half;
#pragma unroll
            for (int rt = 0; rt < 2; rt++)
                act[rt] = rbf8(xb[p * C_ + cb0 + rt * 32]);
        } else {                         // silu: 8 strided-but-coalesced loads
            int tl = t - 98;
#pragma unroll
            for (int rt = 0; rt < 2; rt++) {
                float v[8];
#pragma unroll
                for (int j = 0; j < 8; j++) {
                    int p = tl * 16 + half * 8 + j;
                    v[j] = (p < P_) ? xb[p * C_ + cb0 + rt * 32] : 0.f;
                }
                act[rt] = silu8(v);
            }
        }
        const short8* wt = wp + ((size_t)t * NT1 + ng * 6) * 64 + lane;
#pragma unroll
        for (int nt = 0; nt < 6; nt++) {
            short8 wf = wt[nt * 64];
            acc[0][nt] = __builtin_amdgcn_mfma_f32_32x32x16_bf16(wf, act[0], acc[0][nt], 0, 0, 0);
            acc[1][nt] = __builtin_amdgcn_mfma_f32_32x32x16_bf16(wf, act[1], acc[1][nt], 0, 0, 0);
        }
    }

    // epilogue: h1t[n][r], n = tile + (reg&3)+8*(reg>>2)+4*half, r = rbase (+rt*32)
    int rbase = blk * 128 + rg * 64 + l31;
#pragma unroll
    for (int nt = 0; nt < 6; nt++) {
        int n0 = (ng * 6 + nt) * 32 + 4 * half;
#pragma unroll
        for (int reg = 0; reg < 16; reg++) {
            int n = n0 + (reg & 3) + 8 * (reg >> 2);
            float bv = b1[n];
#pragma unroll
            for (int rt = 0; rt < 2; rt++) {
                h1t[(size_t)n * M_ + rbase + rt * 32] = f2bf_rne(acc[rt][nt][reg] + bv);
            }
        }
    }
}

// fc2: D[p][r] = W2 * act(h1)^T; reads h1t coalesced, writes out[b,p,c] + skip.
__global__ __launch_bounds__(256, 2)
void fc2_kernel(const unsigned short* __restrict__ h1t,
                const unsigned short* __restrict__ w2p,
                const float* __restrict__ b2,
                const float* __restrict__ x,
                float* __restrict__ out) {
    int blk = blockIdx.x;
    int b   = blk / 6;
    int c0  = (blk % 6) * 128;
    int tid  = threadIdx.x;
    int wave = tid >> 6, lane = tid & 63;
    int rg = wave >> 1, ng = wave & 1;
    int half = lane >> 5, l31 = lane & 31;
    int nt0 = ng * 4;
    int ntn = 4 - ng;                    // 4 tiles for ng=0, 3 for ng=1
    int rbase = blk * 128 + rg * 64 + l31;   // + rt*32

    f32x16 acc[2][4];
#pragma unroll
    for (int rt = 0; rt < 2; rt++)
#pragma unroll
        for (int nt = 0; nt < 4; nt++)
#pragma unroll
            for (int i = 0; i < 16; i++) acc[rt][nt][i] = 0.f;

    const short8* wp = (const short8*)w2p;
    for (int t = 0; t < KT2; t++) {
        short8 act[2];
        if (t < 192) {                   // rbf over h1t, coalesced 64B segments
            int s = 2 * t + half;
#pragma unroll
            for (int rt = 0; rt < 2; rt++)
                act[rt] = rbf8(bf2f(h1t[(size_t)s * M_ + rbase + rt * 32]));
        } else {                         // silu over h1t
            int tl = t - 192;
#pragma unroll
            for (int rt = 0; rt < 2; rt++) {
                float v[8];
#pragma unroll
                for (int j = 0; j < 8; j++) {
                    int q = tl * 16 + half * 8 + j;
                    v[j] = bf2f(h1t[(size_t)q * M_ + rbase + rt * 32]);
                }
                act[rt] = silu8(v);
            }
        }
        const short8* wt = wp + ((size_t)t * NT2 + nt0) * 64 + lane;
#pragma unroll
        for (int nt = 0; nt < 4; nt++) {
            if (nt < ntn) {
                short8 wf = wt[nt * 64];
                acc[0][nt] = __builtin_amdgcn_mfma_f32_32x32x16_bf16(wf, act[0], acc[0][nt], 0, 0, 0);
                acc[1][nt] = __builtin_amdgcn_mfma_f32_32x32x16_bf16(wf, act[1], acc[1][nt], 0, 0, 0);
            }
        }
    }

    // epilogue: out[b,p,c] = acc + b2[p] + x[b,p,c]; c = c0+rg*64+rt*32+l31 (coalesced)
#pragma unroll
    for (int nt = 0; nt < 4; nt++) {
        if (nt < ntn) {
            int p0 = (nt0 + nt) * 32 + 4 * half;
#pragma unroll
            for (int reg = 0; reg < 16; reg++) {
                int p = p0 + (reg & 3) + 8 * (reg >> 2);
                if (p < P_) {
                    float bv = b2[p];
#pragma unroll
                    for (int rt = 0; rt < 2; rt++) {
                        size_t off = ((size_t)b * P_ + p) * C_ + c0 + rg * 64 + rt * 32 + l31;
                        out[off] = acc[rt][nt][reg] + bv + x[off];
                    }
                }
            }
        }
    }
}

extern "C" void kernel_launch(void* const* d_in, const int* in_sizes, int n_in,
                              void* d_out, int out_size, void* d_ws, size_t ws_size,
                              hipStream_t stream) {
    const float* x   = (const float*)d_in[0];
    const float* w1s = (const float*)d_in[1];
    const float* w1b = (const float*)d_in[2];
    const float* b1  = (const float*)d_in[3];
    const float* w2s = (const float*)d_in[4];
    const float* w2b = (const float*)d_in[5];
    const float* b2  = (const float*)d_in[6];
    float* out = (float*)d_out;

    unsigned short* h1t = (unsigned short*)d_ws;            // 37.75 MB bf16 [n][r]
    unsigned short* w1p = h1t + H1_ELEMS;                   // 1.38 MB
    unsigned short* w2p = w1p + W1P_ELEMS;                  // 1.55 MB (total ~40.7 MB)

    pack_w_kernel<<<(W1P_ELEMS + W2P_ELEMS) / 256, 256, 0, stream>>>(w1s, w1b, w2s, w2b, w1p, w2p);
    fc1_kernel<<<(M_ / 128), 256, 0, stream>>>(x, w1p, b1, h1t);
    fc2_kernel<<<(M_ / 128), 256, 0, stream>>>(h1t, w2p, b2, x, out);
}

// Round 4
// 331.787 us; speedup vs baseline: 1.8176x; 1.5994x over previous
//
#include <hip/hip_runtime.h>
#include <cstdint>

#define B_  64
#define P_  196
#define C_  768
#define HS_ 384
#define M_  49152

// K-chunk = 16 scalars -> 8 rbf tiles (k16) + 1 silu tile per chunk.
// fc1: 13 chunks (196 p -> 12 full + tail{2 rbf,1 silu}) => KT1 = 12*9+3 = 111 tiles
// fc2: 24 chunks (384 s) => KT2 = 216 tiles
#define NC1 13
#define KT1 111
#define NT1 12
#define NC2 24
#define KT2 216
#define NT2 7

#define H1_ELEMS  ((size_t)M_ * HS_)        // bf16 h1 transposed [n][r]
#define W1P_ELEMS ((size_t)KT1 * NT1 * 512) // 681,984
#define W2P_ELEMS ((size_t)KT2 * NT2 * 512) // 774,144

typedef __attribute__((ext_vector_type(8)))  short short8;
typedef __attribute__((ext_vector_type(16))) float f32x16;

static __device__ __forceinline__ float bf2f(unsigned short u) {
    union { unsigned int i; float f; } v; v.i = ((unsigned int)u) << 16; return v.f;
}
static __device__ __forceinline__ unsigned short f2bf_rne(float f) {
    union { float f; unsigned int i; } v; v.f = f;
    unsigned int r = v.i + 0x7FFFu + ((v.i >> 16) & 1u);
    return (unsigned short)(r >> 16);
}
static __device__ __forceinline__ unsigned int pack2(float a, float b) {
    unsigned int ua = __float_as_uint(a) + 0x8000u;
    unsigned int ub = __float_as_uint(b) + 0x8000u;
    return __builtin_amdgcn_perm(ub, ua, 0x07060302u);  // [a.hi16 | b.hi16]
}
// 8 RBF basis of one scalar: exp(-((s-g_j)*3.5)^2), g_j = -1 + j*2/7
static __device__ __forceinline__ short8 rbf8(float s) {
    float t0 = 3.5f * s + 3.5f;               // d_j = t0 - j
    union { short8 s8; unsigned int u[4]; } r;
#pragma unroll
    for (int q = 0; q < 4; q++) {
        float d0 = t0 - (float)(2 * q);
        float d1 = t0 - (float)(2 * q + 1);
        r.u[q] = pack2(__expf(-d0 * d0), __expf(-d1 * d1));
    }
    return r.s8;
}
static __device__ __forceinline__ unsigned int silu2(float a, float b) {
    float fa = a * __builtin_amdgcn_rcpf(1.f + __expf(-a));
    float fb = b * __builtin_amdgcn_rcpf(1.f + __expf(-b));
    return pack2(fa, fb);
}

// Weights packed as A-operand frags in consumption order:
// w[tt][nt][lane][j] = W[n = nt*32+(lane&31)][k_logical(tt, khalf=lane>>5, j)]
// chunk cc tiles: ktl 0..7 rbf (scalar = cc*16+ktl*2+khalf, j = grid idx),
//                 ktl 8 silu (scalar = cc*16+khalf*8+j). Out-of-range -> 0.
__global__ void pack_w_kernel(const float* __restrict__ w1s,
                              const float* __restrict__ w1b,
                              const float* __restrict__ w2s,
                              const float* __restrict__ w2b,
                              unsigned short* __restrict__ w1p,
                              unsigned short* __restrict__ w2p) {
    size_t idx = (size_t)blockIdx.x * 256 + threadIdx.x;
    if (idx < W1P_ELEMS) {
        int j    = idx & 7;
        int lane = (idx >> 3) & 63;
        int lin  = idx >> 9;             // tt*NT1 + nt
        int nt   = lin % NT1;
        int tt   = lin / NT1;
        int cc   = (tt < 108) ? tt / 9 : 12;
        int kk   = (tt < 108) ? tt % 9 : (tt - 108);
        int ktl  = (cc < 12) ? kk : ((kk < 2) ? kk : 8);
        int n = nt * 32 + (lane & 31);
        int khalf = lane >> 5;
        float v = 0.f;
        if (ktl < 8) {                   // rbf: k = p*8 + j
            int p = cc * 16 + ktl * 2 + khalf;
            if (p < P_) v = w1s[(size_t)n * 1568 + p * 8 + j];
        } else {                         // silu: k = 1568 + p
            int p = cc * 16 + khalf * 8 + j;
            if (p < P_) v = w1b[(size_t)n * 196 + p];
        }
        w1p[idx] = f2bf_rne(v);
    } else {
        size_t idx2 = idx - W1P_ELEMS;
        if (idx2 < W2P_ELEMS) {
            int j    = idx2 & 7;
            int lane = (idx2 >> 3) & 63;
            int lin  = idx2 >> 9;        // tt*NT2 + nt
            int nt   = lin % NT2;
            int tt   = lin / NT2;
            int cc   = tt / 9;
            int ktl  = tt % 9;
            int n = nt * 32 + (lane & 31);
            int khalf = lane >> 5;
            float v = 0.f;
            if (n < P_) {
                if (ktl < 8) {           // rbf: k = s*8 + j
                    int s = cc * 16 + ktl * 2 + khalf;
                    v = w2s[(size_t)n * 3072 + s * 8 + j];
                } else {                 // silu: k = 3072 + s
                    int s = cc * 16 + khalf * 8 + j;
                    v = w2b[(size_t)n * 384 + s];
                }
            }
            w2p[idx2] = f2bf_rne(v);
        }
    }
}

// frag LDS layout (ushort units): [buf 2][tile 9][rt 2][lane 64 * 8]
// tile stride 1024, rt stride 512, buf stride 9216; total 36,864 B.
#define FB_  9216

// fc1: D[n][r] = W1 * act(x)^T over rows r = b*768+c; writes h1t[n][r].
__global__ __launch_bounds__(256, 2)
void fc1_kernel(const float* __restrict__ x,
                const unsigned short* __restrict__ w1p,
                const float* __restrict__ b1,
                unsigned short* __restrict__ h1t) {
    __shared__ __align__(16) unsigned short frag[2 * FB_];
    int blk = blockIdx.x;
    int tid = threadIdx.x;
    int b   = blk / 12;
    int c0  = (blk % 12) * 64;
    const float* xb = x + (size_t)b * (P_ * C_);

    // producer role
    int pr  = tid & 63;                  // row (c offset) 0..63
    int sg  = tid >> 6;                  // scalar-group 0..3
    int prt = pr >> 5, pl31 = pr & 31;
    int pbase_rbf  = (prt << 9) + pl31 * 8;           // + (sl&1)*256 + (sl>>1)*1024
    int pbase_silu = 8 * 1024 + (prt << 9) + (((sg >> 1) << 5) | pl31) * 8 + (sg & 1) * 4;

    // consumer role
    int wave = tid >> 6, lane = tid & 63;
    int l31 = lane & 31, half = lane >> 5;
    int nt0 = wave * 3;

    f32x16 acc[2][3];
#pragma unroll
    for (int rt = 0; rt < 2; rt++)
#pragma unroll
        for (int nt = 0; nt < 3; nt++)
#pragma unroll
            for (int i = 0; i < 16; i++) acc[rt][nt][i] = 0.f;

    const short8* wp = (const short8*)w1p;

    float raw[4];
#pragma unroll
    for (int i = 0; i < 4; i++) {
        int p = sg * 4 + i;              // chunk 0: p < 16, valid
        raw[i] = xb[(size_t)p * C_ + c0 + pr];
    }

    for (int cc = 0; cc < NC1; cc++) {
        int fb = (cc & 1) * FB_;
        // --- produce fragments for chunk cc ---
#pragma unroll
        for (int i = 0; i < 4; i++) {
            int sl = sg * 4 + i;
            *(short8*)&frag[fb + (sl >> 1) * 1024 + ((sl & 1) << 8) + pbase_rbf] = rbf8(raw[i]);
        }
        {
            union { unsigned int u[2]; } sv;
            sv.u[0] = silu2(raw[0], raw[1]);
            sv.u[1] = silu2(raw[2], raw[3]);
            *(uint2*)&frag[fb + pbase_silu] = *(uint2*)sv.u;
        }
        // --- issue raw loads for chunk cc+1 (overlap consume) ---
        float nraw[4];
#pragma unroll
        for (int i = 0; i < 4; i++) {
            int p = (cc + 1) * 16 + sg * 4 + i;
            p = (p < P_) ? p : (P_ - 1);      // clamp; pad weights are zero
            nraw[i] = xb[(size_t)p * C_ + c0 + pr];
        }
        __syncthreads();
        // --- consume ---
        int ntile = (cc < 12) ? 9 : 3;
        short8 wcur[3];
        {
            const short8* wt = wp + ((size_t)(cc * 9) * NT1 + nt0) * 64 + lane;
#pragma unroll
            for (int nt = 0; nt < 3; nt++) wcur[nt] = wt[nt * 64];
        }
        for (int kk = 0; kk < ntile; kk++) {
            int ktl = (cc < 12) ? kk : ((kk < 2) ? kk : 8);
            short8 a0 = *(const short8*)&frag[fb + ktl * 1024 +       lane * 8];
            short8 a1 = *(const short8*)&frag[fb + ktl * 1024 + 512 + lane * 8];
            if (kk + 1 < ntile) {
                short8 wnxt[3];
                const short8* wt = wp + ((size_t)(cc * 9 + kk + 1) * NT1 + nt0) * 64 + lane;
#pragma unroll
                for (int nt = 0; nt < 3; nt++) wnxt[nt] = wt[nt * 64];
#pragma unroll
                for (int nt = 0; nt < 3; nt++) {
                    acc[0][nt] = __builtin_amdgcn_mfma_f32_32x32x16_bf16(wcur[nt], a0, acc[0][nt], 0, 0, 0);
                    acc[1][nt] = __builtin_amdgcn_mfma_f32_32x32x16_bf16(wcur[nt], a1, acc[1][nt], 0, 0, 0);
                }
#pragma unroll
                for (int nt = 0; nt < 3; nt++) wcur[nt] = wnxt[nt];
            } else {
#pragma unroll
                for (int nt = 0; nt < 3; nt++) {
                    acc[0][nt] = __builtin_amdgcn_mfma_f32_32x32x16_bf16(wcur[nt], a0, acc[0][nt], 0, 0, 0);
                    acc[1][nt] = __builtin_amdgcn_mfma_f32_32x32x16_bf16(wcur[nt], a1, acc[1][nt], 0, 0, 0);
                }
            }
        }
#pragma unroll
        for (int i = 0; i < 4; i++) raw[i] = nraw[i];
    }

    // epilogue: h1t[n][r], n = tile*32 + (reg&3)+8*(reg>>2)+4*half, r = blk*64+rt*32+l31
#pragma unroll
    for (int nt = 0; nt < 3; nt++) {
        int n0 = (nt0 + nt) * 32 + 4 * half;
#pragma unroll
        for (int reg = 0; reg < 16; reg++) {
            int n = n0 + (reg & 3) + 8 * (reg >> 2);
            float bv = b1[n];
#pragma unroll
            for (int rt = 0; rt < 2; rt++) {
                h1t[(size_t)n * M_ + blk * 64 + rt * 32 + l31] = f2bf_rne(acc[rt][nt][reg] + bv);
            }
        }
    }
}

// fc2: D[p][r] = W2 * act(h1)^T; reads h1t[s][r] once; out = D + b2 + x (fp32 skip).
__global__ __launch_bounds__(256, 2)
void fc2_kernel(const unsigned short* __restrict__ h1t,
                const unsigned short* __restrict__ w2p,
                const float* __restrict__ b2,
                const float* __restrict__ x,
                float* __restrict__ out) {
    __shared__ __align__(16) unsigned short frag[2 * FB_];
    int blk = blockIdx.x;
    int tid = threadIdx.x;
    int rbase = blk * 64;

    int pr  = tid & 63;
    int sg  = tid >> 6;
    int prt = pr >> 5, pl31 = pr & 31;
    int pbase_rbf  = (prt << 9) + pl31 * 8;
    int pbase_silu = 8 * 1024 + (prt << 9) + (((sg >> 1) << 5) | pl31) * 8 + (sg & 1) * 4;

    int wave = tid >> 6, lane = tid & 63;
    int l31 = lane & 31, half = lane >> 5;
    int nt0 = wave * 2;
    int ntn = (wave < 3) ? 2 : 1;

    f32x16 acc[2][2];
#pragma unroll
    for (int rt = 0; rt < 2; rt++)
#pragma unroll
        for (int nt = 0; nt < 2; nt++)
#pragma unroll
            for (int i = 0; i < 16; i++) acc[rt][nt][i] = 0.f;

    const short8* wp = (const short8*)w2p;

    float raw[4];
#pragma unroll
    for (int i = 0; i < 4; i++) {
        int s = sg * 4 + i;
        raw[i] = bf2f(h1t[(size_t)s * M_ + rbase + pr]);
    }

    for (int cc = 0; cc < NC2; cc++) {
        int fb = (cc & 1) * FB_;
#pragma unroll
        for (int i = 0; i < 4; i++) {
            int sl = sg * 4 + i;
            *(short8*)&frag[fb + (sl >> 1) * 1024 + ((sl & 1) << 8) + pbase_rbf] = rbf8(raw[i]);
        }
        {
            union { unsigned int u[2]; } sv;
            sv.u[0] = silu2(raw[0], raw[1]);
            sv.u[1] = silu2(raw[2], raw[3]);
            *(uint2*)&frag[fb + pbase_silu] = *(uint2*)sv.u;
        }
        float nraw[4];
#pragma unroll
        for (int i = 0; i < 4; i++) {
            int s = (cc + 1) * 16 + sg * 4 + i;
            s = (s < HS_) ? s : (HS_ - 1);    // clamp (last iter only; unused)
            nraw[i] = bf2f(h1t[(size_t)s * M_ + rbase + pr]);
        }
        __syncthreads();
        short8 wcur[2];
        {
            const short8* wt = wp + ((size_t)(cc * 9) * NT2 + nt0) * 64 + lane;
#pragma unroll
            for (int nt = 0; nt < 2; nt++) if (nt < ntn) wcur[nt] = wt[nt * 64];
        }
        for (int kk = 0; kk < 9; kk++) {
            short8 a0 = *(const short8*)&frag[fb + kk * 1024 +       lane * 8];
            short8 a1 = *(const short8*)&frag[fb + kk * 1024 + 512 + lane * 8];
            if (kk < 8) {
                short8 wnxt[2];
                const short8* wt = wp + ((size_t)(cc * 9 + kk + 1) * NT2 + nt0) * 64 + lane;
#pragma unroll
                for (int nt = 0; nt < 2; nt++) if (nt < ntn) wnxt[nt] = wt[nt * 64];
#pragma unroll
                for (int nt = 0; nt < 2; nt++) {
                    if (nt < ntn) {
                        acc[0][nt] = __builtin_amdgcn_mfma_f32_32x32x16_bf16(wcur[nt], a0, acc[0][nt], 0, 0, 0);
                        acc[1][nt] = __builtin_amdgcn_mfma_f32_32x32x16_bf16(wcur[nt], a1, acc[1][nt], 0, 0, 0);
                    }
                }
#pragma unroll
                for (int nt = 0; nt < 2; nt++) if (nt < ntn) wcur[nt] = wnxt[nt];
            } else {
#pragma unroll
                for (int nt = 0; nt < 2; nt++) {
                    if (nt < ntn) {
                        acc[0][nt] = __builtin_amdgcn_mfma_f32_32x32x16_bf16(wcur[nt], a0, acc[0][nt], 0, 0, 0);
                        acc[1][nt] = __builtin_amdgcn_mfma_f32_32x32x16_bf16(wcur[nt], a1, acc[1][nt], 0, 0, 0);
                    }
                }
            }
        }
#pragma unroll
        for (int i = 0; i < 4; i++) raw[i] = nraw[i];
    }

    // epilogue: out[b,p,c] = acc + b2[p] + x[b,p,c]
    int b = blk / 12;
    int c0 = (blk % 12) * 64;
#pragma unroll
    for (int nt = 0; nt < 2; nt++) {
        if (nt < ntn) {
            int p0 = (nt0 + nt) * 32 + 4 * half;
#pragma unroll
            for (int reg = 0; reg < 16; reg++) {
                int p = p0 + (reg & 3) + 8 * (reg >> 2);
                if (p < P_) {
                    float bv = b2[p];
#pragma unroll
                    for (int rt = 0; rt < 2; rt++) {
                        size_t off = ((size_t)b * P_ + p) * C_ + c0 + rt * 32 + l31;
                        out[off] = acc[rt][nt][reg] + bv + x[off];
                    }
                }
            }
        }
    }
}

extern "C" void kernel_launch(void* const* d_in, const int* in_sizes, int n_in,
                              void* d_out, int out_size, void* d_ws, size_t ws_size,
                              hipStream_t stream) {
    const float* x   = (const float*)d_in[0];
    const float* w1s = (const float*)d_in[1];
    const float* w1b = (const float*)d_in[2];
    const float* b1  = (const float*)d_in[3];
    const float* w2s = (const float*)d_in[4];
    const float* w2b = (const float*)d_in[5];
    const float* b2  = (const float*)d_in[6];
    float* out = (float*)d_out;

    unsigned short* h1t = (unsigned short*)d_ws;            // 37.75 MB bf16 [n][r]
    unsigned short* w1p = h1t + H1_ELEMS;
    unsigned short* w2p = w1p + W1P_ELEMS;                  // total ~40.7 MB

    int pack_blocks = (int)((W1P_ELEMS + W2P_ELEMS) / 256); // exact multiple
    pack_w_kernel<<<pack_blocks, 256, 0, stream>>>(w1s, w1b, w2s, w2b, w1p, w2p);
    fc1_kernel<<<M_ / 64, 256, 0, stream>>>(x, w1p, b1, h1t);
    fc2_kernel<<<M_ / 64, 256, 0, stream>>>(h1t, w2p, b2, x, out);
}

// Round 5
// 331.050 us; speedup vs baseline: 1.8217x; 1.0022x over previous
//
#include <hip/hip_runtime.h>
#include <cstdint>

#define B_  64
#define P_  196
#define C_  768
#define HS_ 384
#define M_  49152

// K-chunk = 16 scalars -> 8 rbf tiles (k16) + 1 silu tile per chunk.
// fc1: 13 chunks (12 full + tail{2 rbf,1 silu}) => KT1 = 12*9+3 = 111 tiles
// fc2: 24 chunks (384 s) => KT2 = 216 tiles
#define NC1 13
#define KT1 111
#define NT1 12
#define NC2 24
#define KT2 216
#define NT2 7

#define H1_ELEMS  ((size_t)M_ * HS_)        // bf16 h1 transposed [n][r]
#define W1P_ELEMS ((size_t)KT1 * NT1 * 512) // 681,984
#define W2P_ELEMS ((size_t)KT2 * NT2 * 512) // 774,144

typedef __attribute__((ext_vector_type(8)))  short short8;
typedef __attribute__((ext_vector_type(16))) float f32x16;

#define MFMA(w, a, c) __builtin_amdgcn_mfma_f32_32x32x16_bf16((w), (a), (c), 0, 0, 0)

static __device__ __forceinline__ float bf2f(unsigned short u) {
    union { unsigned int i; float f; } v; v.i = ((unsigned int)u) << 16; return v.f;
}
static __device__ __forceinline__ unsigned short f2bf_rne(float f) {
    union { float f; unsigned int i; } v; v.f = f;
    unsigned int r = v.i + 0x7FFFu + ((v.i >> 16) & 1u);
    return (unsigned short)(r >> 16);
}
static __device__ __forceinline__ unsigned int pack2(float a, float b) {
    unsigned int ua = __float_as_uint(a) + 0x8000u;
    unsigned int ub = __float_as_uint(b) + 0x8000u;
    return __builtin_amdgcn_perm(ub, ua, 0x07060302u);  // [a.hi16 | b.hi16]
}
// 8 RBF basis of one scalar: exp(-((s-g_j)*3.5)^2), g_j = -1 + j*2/7
static __device__ __forceinline__ short8 rbf8(float s) {
    float t0 = 3.5f * s + 3.5f;               // d_j = t0 - j
    union { short8 s8; unsigned int u[4]; } r;
#pragma unroll
    for (int q = 0; q < 4; q++) {
        float d0 = t0 - (float)(2 * q);
        float d1 = t0 - (float)(2 * q + 1);
        r.u[q] = pack2(__expf(-d0 * d0), __expf(-d1 * d1));
    }
    return r.s8;
}
static __device__ __forceinline__ unsigned int silu2(float a, float b) {
    float fa = a * __builtin_amdgcn_rcpf(1.f + __expf(-a));
    float fb = b * __builtin_amdgcn_rcpf(1.f + __expf(-b));
    return pack2(fa, fb);
}

// Weights packed as A-operand frags in consumption order:
// w[tt][nt][lane][j] = W[n = nt*32+(lane&31)][k_logical(tt, khalf=lane>>5, j)]
// chunk cc tiles: ktl 0..7 rbf (scalar = cc*16+ktl*2+khalf, j = grid idx),
//                 ktl 8 silu (scalar = cc*16+khalf*8+j). Out-of-range -> 0.
__global__ void pack_w_kernel(const float* __restrict__ w1s,
                              const float* __restrict__ w1b,
                              const float* __restrict__ w2s,
                              const float* __restrict__ w2b,
                              unsigned short* __restrict__ w1p,
                              unsigned short* __restrict__ w2p) {
    size_t idx = (size_t)blockIdx.x * 256 + threadIdx.x;
    if (idx < W1P_ELEMS) {
        int j    = idx & 7;
        int lane = (idx >> 3) & 63;
        int lin  = idx >> 9;             // tt*NT1 + nt
        int nt   = lin % NT1;
        int tt   = lin / NT1;
        int cc   = (tt < 108) ? tt / 9 : 12;
        int kk   = (tt < 108) ? tt % 9 : (tt - 108);
        int ktl  = (cc < 12) ? kk : ((kk < 2) ? kk : 8);
        int n = nt * 32 + (lane & 31);
        int khalf = lane >> 5;
        float v = 0.f;
        if (ktl < 8) {                   // rbf: k = p*8 + j
            int p = cc * 16 + ktl * 2 + khalf;
            if (p < P_) v = w1s[(size_t)n * 1568 + p * 8 + j];
        } else {                         // silu: k = 1568 + p
            int p = cc * 16 + khalf * 8 + j;
            if (p < P_) v = w1b[(size_t)n * 196 + p];
        }
        w1p[idx] = f2bf_rne(v);
    } else {
        size_t idx2 = idx - W1P_ELEMS;
        if (idx2 < W2P_ELEMS) {
            int j    = idx2 & 7;
            int lane = (idx2 >> 3) & 63;
            int lin  = idx2 >> 9;        // tt*NT2 + nt
            int nt   = lin % NT2;
            int tt   = lin / NT2;
            int cc   = tt / 9;
            int ktl  = tt % 9;
            int n = nt * 32 + (lane & 31);
            int khalf = lane >> 5;
            float v = 0.f;
            if (n < P_) {
                if (ktl < 8) {           // rbf: k = s*8 + j
                    int s = cc * 16 + ktl * 2 + khalf;
                    v = w2s[(size_t)n * 3072 + s * 8 + j];
                } else {                 // silu: k = 3072 + s
                    int s = cc * 16 + khalf * 8 + j;
                    v = w2b[(size_t)n * 384 + s];
                }
            }
            w2p[idx2] = f2bf_rne(v);
        }
    }
}

// frag LDS layout (ushort units): [buf 2][tile 9][rt 2][lane 64 * 8]
// tile stride 1024, rt stride 512, buf stride 9216 ushorts; total 36,864 B.
#define FB_  9216

// fc1: D[n][r] = W1 * act(x)^T over rows r = b*768+c; writes h1t[n][r].
__global__ __launch_bounds__(256, 2)
void fc1_kernel(const float* __restrict__ x,
                const unsigned short* __restrict__ w1p,
                const float* __restrict__ b1,
                unsigned short* __restrict__ h1t) {
    __shared__ __align__(16) unsigned short frag[2 * FB_];
    int blk = blockIdx.x;
    int tid = threadIdx.x;
    int b   = blk / 12;
    int c0  = (blk % 12) * 64;
    const float* xb = x + (size_t)b * (P_ * C_);

    // producer role
    int pr  = tid & 63;                  // row (c offset) 0..63
    int sg  = tid >> 6;                  // scalar-group 0..3
    int prt = pr >> 5, pl31 = pr & 31;
    int pbase_rbf  = (prt << 9) + pl31 * 8;
    int pbase_silu = 8 * 1024 + (prt << 9) + (((sg >> 1) << 5) | pl31) * 8 + (sg & 1) * 4;

    // consumer role
    int wave = tid >> 6, lane = tid & 63;
    int l31 = lane & 31, half = lane >> 5;
    int nt0 = wave * 3;

    f32x16 acc[2][3];
#pragma unroll
    for (int rt = 0; rt < 2; rt++)
#pragma unroll
        for (int nt = 0; nt < 3; nt++)
#pragma unroll
            for (int i = 0; i < 16; i++) acc[rt][nt][i] = 0.f;

    const short8* wp = (const short8*)w1p;

    // raw prefetch depth 2 chunks
    float raw0[4], raw1[4];
#pragma unroll
    for (int i = 0; i < 4; i++) {
        raw0[i] = xb[(size_t)(sg * 4 + i) * C_ + c0 + pr];
        raw1[i] = xb[(size_t)(16 + sg * 4 + i) * C_ + c0 + pr];
    }

    short8 wbuf[3][3];

    for (int cc = 0; cc < NC1; cc++) {
        int fb = (cc & 1) * FB_;
        const short8* wt0 = wp + ((size_t)(cc * 9) * NT1 + nt0) * 64 + lane;
        // weight preload depth-3 BEFORE produce (exp-VALU hides L2 latency)
#pragma unroll
        for (int d = 0; d < 3; d++) {
            const short8* wt = wt0 + (size_t)d * (NT1 * 64);
            wbuf[d][0] = wt[0]; wbuf[d][1] = wt[64]; wbuf[d][2] = wt[128];
        }
        // --- produce fragments for chunk cc ---
#pragma unroll
        for (int i = 0; i < 4; i++) {
            int sl = sg * 4 + i;
            *(short8*)&frag[fb + (sl >> 1) * 1024 + ((sl & 1) << 8) + pbase_rbf] = rbf8(raw0[i]);
        }
        {
            uint2 sv;
            sv.x = silu2(raw0[0], raw0[1]);
            sv.y = silu2(raw0[2], raw0[3]);
            *(uint2*)&frag[fb + pbase_silu] = sv;
        }
        // --- raw loads for chunk cc+2 ---
        float raw2[4];
#pragma unroll
        for (int i = 0; i < 4; i++) {
            int p = (cc + 2) * 16 + sg * 4 + i;
            p = (p < P_) ? p : (P_ - 1);      // clamp; pad weights are zero
            raw2[i] = xb[(size_t)p * C_ + c0 + pr];
        }
        __syncthreads();
        // --- consume ---
        const unsigned short* fg = &frag[fb];
        if (cc < 12) {
            short8 a0 = *(const short8*)&fg[lane * 8];
            short8 a1 = *(const short8*)&fg[512 + lane * 8];
#pragma unroll
            for (int kk = 0; kk < 9; kk++) {
                short8 na0, na1;
                if (kk < 8) {
                    na0 = *(const short8*)&fg[(kk + 1) * 1024 + lane * 8];
                    na1 = *(const short8*)&fg[(kk + 1) * 1024 + 512 + lane * 8];
                }
                short8 w0 = wbuf[kk % 3][0], w1 = wbuf[kk % 3][1], w2 = wbuf[kk % 3][2];
                if (kk + 3 < 9) {         // rolling depth-3 weight prefetch
                    const short8* wt = wt0 + (size_t)(kk + 3) * (NT1 * 64);
                    wbuf[kk % 3][0] = wt[0]; wbuf[kk % 3][1] = wt[64]; wbuf[kk % 3][2] = wt[128];
                }
                acc[0][0] = MFMA(w0, a0, acc[0][0]); acc[1][0] = MFMA(w0, a1, acc[1][0]);
                acc[0][1] = MFMA(w1, a0, acc[0][1]); acc[1][1] = MFMA(w1, a1, acc[1][1]);
                acc[0][2] = MFMA(w2, a0, acc[0][2]); acc[1][2] = MFMA(w2, a1, acc[1][2]);
                if (kk < 8) { a0 = na0; a1 = na1; }
            }
        } else {                          // tail chunk: tiles ktl {0,1,8}
#pragma unroll
            for (int kk = 0; kk < 3; kk++) {
                int ktl = (kk < 2) ? kk : 8;
                short8 a0 = *(const short8*)&fg[ktl * 1024 + lane * 8];
                short8 a1 = *(const short8*)&fg[ktl * 1024 + 512 + lane * 8];
                short8 w0 = wbuf[kk][0], w1 = wbuf[kk][1], w2 = wbuf[kk][2];
                acc[0][0] = MFMA(w0, a0, acc[0][0]); acc[1][0] = MFMA(w0, a1, acc[1][0]);
                acc[0][1] = MFMA(w1, a0, acc[0][1]); acc[1][1] = MFMA(w1, a1, acc[1][1]);
                acc[0][2] = MFMA(w2, a0, acc[0][2]); acc[1][2] = MFMA(w2, a1, acc[1][2]);
            }
        }
#pragma unroll
        for (int i = 0; i < 4; i++) { raw0[i] = raw1[i]; raw1[i] = raw2[i]; }
    }

    // epilogue: h1t[n][r], n = tile*32 + (reg&3)+8*(reg>>2)+4*half, r = blk*64+rt*32+l31
#pragma unroll
    for (int nt = 0; nt < 3; nt++) {
        int n0 = (nt0 + nt) * 32 + 4 * half;
#pragma unroll
        for (int reg = 0; reg < 16; reg++) {
            int n = n0 + (reg & 3) + 8 * (reg >> 2);
            float bv = b1[n];
#pragma unroll
            for (int rt = 0; rt < 2; rt++) {
                h1t[(size_t)n * M_ + blk * 64 + rt * 32 + l31] = f2bf_rne(acc[rt][nt][reg] + bv);
            }
        }
    }
}

// fc2: D[p][r] = W2 * act(h1)^T; reads h1t[s][r] once; out = D + b2 + x (fp32 skip).
__global__ __launch_bounds__(256, 2)
void fc2_kernel(const unsigned short* __restrict__ h1t,
                const unsigned short* __restrict__ w2p,
                const float* __restrict__ b2,
                const float* __restrict__ x,
                float* __restrict__ out) {
    __shared__ __align__(16) unsigned short frag[2 * FB_];
    int blk = blockIdx.x;
    int tid = threadIdx.x;
    int rbase = blk * 64;

    int pr  = tid & 63;
    int sg  = tid >> 6;
    int prt = pr >> 5, pl31 = pr & 31;
    int pbase_rbf  = (prt << 9) + pl31 * 8;
    int pbase_silu = 8 * 1024 + (prt << 9) + (((sg >> 1) << 5) | pl31) * 8 + (sg & 1) * 4;

    int wave = tid >> 6, lane = tid & 63;
    int l31 = lane & 31, half = lane >> 5;
    int nt0 = wave * 2;
    int ntn = (wave < 3) ? 2 : 1;
    int off1 = (ntn > 1) ? 64 : 0;       // wave 3 duplicates its nt0 tile (discarded)

    f32x16 acc[2][2];
#pragma unroll
    for (int rt = 0; rt < 2; rt++)
#pragma unroll
        for (int nt = 0; nt < 2; nt++)
#pragma unroll
            for (int i = 0; i < 16; i++) acc[rt][nt][i] = 0.f;

    const short8* wp = (const short8*)w2p;

    float raw0[4], raw1[4];
#pragma unroll
    for (int i = 0; i < 4; i++) {
        raw0[i] = bf2f(h1t[(size_t)(sg * 4 + i) * M_ + rbase + pr]);
        raw1[i] = bf2f(h1t[(size_t)(16 + sg * 4 + i) * M_ + rbase + pr]);
    }

    short8 wbuf[4][2];

    for (int cc = 0; cc < NC2; cc++) {
        int fb = (cc & 1) * FB_;
        const short8* wt0 = wp + ((size_t)(cc * 9) * NT2 + nt0) * 64 + lane;
        // weight preload depth-4 BEFORE produce
#pragma unroll
        for (int d = 0; d < 4; d++) {
            const short8* wt = wt0 + (size_t)d * (NT2 * 64);
            wbuf[d][0] = wt[0]; wbuf[d][1] = wt[off1];
        }
#pragma unroll
        for (int i = 0; i < 4; i++) {
            int sl = sg * 4 + i;
            *(short8*)&frag[fb + (sl >> 1) * 1024 + ((sl & 1) << 8) + pbase_rbf] = rbf8(raw0[i]);
        }
        {
            uint2 sv;
            sv.x = silu2(raw0[0], raw0[1]);
            sv.y = silu2(raw0[2], raw0[3]);
            *(uint2*)&frag[fb + pbase_silu] = sv;
        }
        float raw2[4];
#pragma unroll
        for (int i = 0; i < 4; i++) {
            int s = (cc + 2) * 16 + sg * 4 + i;
            s = (s < HS_) ? s : (HS_ - 1);    // clamp (tail; unused)
            raw2[i] = bf2f(h1t[(size_t)s * M_ + rbase + pr]);
        }
        __syncthreads();
        const unsigned short* fg = &frag[fb];
        short8 a0 = *(const short8*)&fg[lane * 8];
        short8 a1 = *(const short8*)&fg[512 + lane * 8];
#pragma unroll
        for (int kk = 0; kk < 9; kk++) {
            short8 na0, na1;
            if (kk < 8) {
                na0 = *(const short8*)&fg[(kk + 1) * 1024 + lane * 8];
                na1 = *(const short8*)&fg[(kk + 1) * 1024 + 512 + lane * 8];
            }
            short8 w0 = wbuf[kk & 3][0], w1 = wbuf[kk & 3][1];
            if (kk < 5) {                 // rolling depth-4 weight prefetch
                const short8* wt = wt0 + (size_t)(kk + 4) * (NT2 * 64);
                wbuf[kk & 3][0] = wt[0]; wbuf[kk & 3][1] = wt[off1];
            }
            acc[0][0] = MFMA(w0, a0, acc[0][0]); acc[1][0] = MFMA(w0, a1, acc[1][0]);
            acc[0][1] = MFMA(w1, a0, acc[0][1]); acc[1][1] = MFMA(w1, a1, acc[1][1]);
            if (kk < 8) { a0 = na0; a1 = na1; }
        }
#pragma unroll
        for (int i = 0; i < 4; i++) { raw0[i] = raw1[i]; raw1[i] = raw2[i]; }
    }

    // epilogue: out[b,p,c] = acc + b2[p] + x[b,p,c]
    int b = blk / 12;
    int c0 = (blk % 12) * 64;
#pragma unroll
    for (int nt = 0; nt < 2; nt++) {
        if (nt < ntn) {
            int p0 = (nt0 + nt) * 32 + 4 * half;
#pragma unroll
            for (int reg = 0; reg < 16; reg++) {
                int p = p0 + (reg & 3) + 8 * (reg >> 2);
                if (p < P_) {
                    float bv = b2[p];
#pragma unroll
                    for (int rt = 0; rt < 2; rt++) {
                        size_t off = ((size_t)b * P_ + p) * C_ + c0 + rt * 32 + l31;
                        out[off] = acc[rt][nt][reg] + bv + x[off];
                    }
                }
            }
        }
    }
}

extern "C" void kernel_launch(void* const* d_in, const int* in_sizes, int n_in,
                              void* d_out, int out_size, void* d_ws, size_t ws_size,
                              hipStream_t stream) {
    const float* x   = (const float*)d_in[0];
    const float* w1s = (const float*)d_in[1];
    const float* w1b = (const float*)d_in[2];
    const float* b1  = (const float*)d_in[3];
    const float* w2s = (const float*)d_in[4];
    const float* w2b = (const float*)d_in[5];
    const float* b2  = (const float*)d_in[6];
    float* out = (float*)d_out;

    unsigned short* h1t = (unsigned short*)d_ws;            // 37.75 MB bf16 [n][r]
    unsigned short* w1p = h1t + H1_ELEMS;
    unsigned short* w2p = w1p + W1P_ELEMS;                  // total ~40.7 MB

    int pack_blocks = (int)((W1P_ELEMS + W2P_ELEMS) / 256); // exact multiple
    pack_w_kernel<<<pack_blocks, 256, 0, stream>>>(w1s, w1b, w2s, w2b, w1p, w2p);
    fc1_kernel<<<M_ / 64, 256, 0, stream>>>(x, w1p, b1, h1t);
    fc2_kernel<<<M_ / 64, 256, 0, stream>>>(h1t, w2p, b2, x, out);
}

// Round 6
// 293.909 us; speedup vs baseline: 2.0519x; 1.1264x over previous
//
#include <hip/hip_runtime.h>
#include <cstdint>

#define B_  64
#define P_  196
#define C_  768
#define HS_ 384
#define M_  49152

// K-chunk = 16 scalars -> 8 rbf tiles (k16) + 1 silu tile per chunk.
// fc1: 13 chunks (12 full + tail{2 rbf,1 silu}) => KT1 = 111 tiles
// fc2: 24 chunks => KT2 = 216 tiles
#define NC1 13
#define KT1 111
#define NT1 12
#define NC2 24
#define KT2 216
#define NT2 7

#define H1_ELEMS  ((size_t)M_ * HS_)
#define W1P_ELEMS ((size_t)KT1 * NT1 * 512) // 681,984
#define W2P_ELEMS ((size_t)KT2 * NT2 * 512) // 774,144

typedef __attribute__((ext_vector_type(8)))  short short8;
typedef __attribute__((ext_vector_type(16))) float f32x16;

#define MFMA(w, a, c) __builtin_amdgcn_mfma_f32_32x32x16_bf16((w), (a), (c), 0, 0, 0)

static __device__ __forceinline__ float bf2f(unsigned short u) {
    union { unsigned int i; float f; } v; v.i = ((unsigned int)u) << 16; return v.f;
}
static __device__ __forceinline__ unsigned short f2bf_rne(float f) {
    union { float f; unsigned int i; } v; v.f = f;
    unsigned int r = v.i + 0x7FFFu + ((v.i >> 16) & 1u);
    return (unsigned short)(r >> 16);
}
static __device__ __forceinline__ unsigned int pack2(float a, float b) {
    unsigned int ua = __float_as_uint(a) + 0x8000u;
    unsigned int ub = __float_as_uint(b) + 0x8000u;
    return __builtin_amdgcn_perm(ub, ua, 0x07060302u);  // [a | b] (a = low ushort)
}
// 8 RBF basis of one scalar: exp(-((s-g_j)*3.5)^2), g_j = -1 + j*2/7
static __device__ __forceinline__ short8 rbf8(float s) {
    float t0 = 3.5f * s + 3.5f;               // d_j = t0 - j
    union { short8 s8; unsigned int u[4]; } r;
#pragma unroll
    for (int q = 0; q < 4; q++) {
        float d0 = t0 - (float)(2 * q);
        float d1 = t0 - (float)(2 * q + 1);
        r.u[q] = pack2(__expf(-d0 * d0), __expf(-d1 * d1));
    }
    return r.s8;
}
static __device__ __forceinline__ unsigned int silu2(float a, float b) {
    float fa = a * __builtin_amdgcn_rcpf(1.f + __expf(-a));
    float fb = b * __builtin_amdgcn_rcpf(1.f + __expf(-b));
    return pack2(fa, fb);
}

// Weights packed as A-operand frags in consumption order (unchanged from R4/R5):
// w[tt][nt][lane][j] = W[n = nt*32+(lane&31)][k_logical(tt, khalf=lane>>5, j)]
__global__ void pack_w_kernel(const float* __restrict__ w1s,
                              const float* __restrict__ w1b,
                              const float* __restrict__ w2s,
                              const float* __restrict__ w2b,
                              unsigned short* __restrict__ w1p,
                              unsigned short* __restrict__ w2p) {
    size_t idx = (size_t)blockIdx.x * 256 + threadIdx.x;
    if (idx < W1P_ELEMS) {
        int j    = idx & 7;
        int lane = (idx >> 3) & 63;
        int lin  = idx >> 9;             // tt*NT1 + nt
        int nt   = lin % NT1;
        int tt   = lin / NT1;
        int cc   = (tt < 108) ? tt / 9 : 12;
        int kk   = (tt < 108) ? tt % 9 : (tt - 108);
        int ktl  = (cc < 12) ? kk : ((kk < 2) ? kk : 8);
        int n = nt * 32 + (lane & 31);
        int khalf = lane >> 5;
        float v = 0.f;
        if (ktl < 8) {
            int p = cc * 16 + ktl * 2 + khalf;
            if (p < P_) v = w1s[(size_t)n * 1568 + p * 8 + j];
        } else {
            int p = cc * 16 + khalf * 8 + j;
            if (p < P_) v = w1b[(size_t)n * 196 + p];
        }
        w1p[idx] = f2bf_rne(v);
    } else {
        size_t idx2 = idx - W1P_ELEMS;
        if (idx2 < W2P_ELEMS) {
            int j    = idx2 & 7;
            int lane = (idx2 >> 3) & 63;
            int lin  = idx2 >> 9;        // tt*NT2 + nt
            int nt   = lin % NT2;
            int tt   = lin / NT2;
            int cc   = tt / 9;
            int ktl  = tt % 9;
            int n = nt * 32 + (lane & 31);
            int khalf = lane >> 5;
            float v = 0.f;
            if (n < P_) {
                if (ktl < 8) {
                    int s = cc * 16 + ktl * 2 + khalf;
                    v = w2s[(size_t)n * 3072 + s * 8 + j];
                } else {
                    int s = cc * 16 + khalf * 8 + j;
                    v = w2b[(size_t)n * 384 + s];
                }
            }
            w2p[idx2] = f2bf_rne(v);
        }
    }
}

// frag LDS: [buf 2][tile 9][rt 2][lane 64 * 8] ushort; FB_ = 9216 ushort/buf.
#define FB_  9216

// fc1: D[n][r] = W1 * act(x)^T; writes h1t[n][r].
__global__ __launch_bounds__(256, 2)
void fc1_kernel(const float* __restrict__ x,
                const unsigned short* __restrict__ w1p,
                const float* __restrict__ b1,
                unsigned short* __restrict__ h1t) {
    __shared__ __align__(16) unsigned short frag[2 * FB_];
    int blk = blockIdx.x;
    int tid = threadIdx.x;
    int b   = blk / 12;
    int c0  = (blk % 12) * 64;
    const float* xb = x + (size_t)b * (P_ * C_);

    int pr  = tid & 63;
    int sg  = tid >> 6;
    int prt = pr >> 5, pl31 = pr & 31;
    int pbase_rbf  = (prt << 9) + pl31 * 8;
    int pbase_silu = 8 * 1024 + (prt << 9) + (((sg >> 1) << 5) | pl31) * 8 + (sg & 1) * 4;

    int wave = sg, lane = tid & 63;
    int l31 = lane & 31, half = lane >> 5;
    int nt0 = wave * 3;

    f32x16 acc[2][3];
#pragma unroll
    for (int rt = 0; rt < 2; rt++)
#pragma unroll
        for (int nt = 0; nt < 3; nt++)
#pragma unroll
            for (int i = 0; i < 16; i++) acc[rt][nt][i] = 0.f;

    const short8* wp = (const short8*)w1p;
    short8 wbuf[3][3];

    auto wload = [&](int d, const short8* wt0, int kk) {
        const short8* wt = wt0 + (size_t)kk * (NT1 * 64);
        wbuf[d][0] = wt[0]; wbuf[d][1] = wt[64]; wbuf[d][2] = wt[128];
    };
    auto produce = [&](int fb, const float (&rb)[4]) {
#pragma unroll
        for (int i = 0; i < 4; i++) {
            int sl = sg * 4 + i;
            *(short8*)&frag[fb + (sl >> 1) * 1024 + ((sl & 1) << 8) + pbase_rbf] = rbf8(rb[i]);
        }
        uint2 sv;
        sv.x = silu2(rb[0], rb[1]);
        sv.y = silu2(rb[2], rb[3]);
        *(uint2*)&frag[fb + pbase_silu] = sv;
    };
    auto do_mfma = [&](short8 w0, short8 w1, short8 w2, short8 a0, short8 a1) {
        acc[0][0] = MFMA(w0, a0, acc[0][0]); acc[1][0] = MFMA(w0, a1, acc[1][0]);
        acc[0][1] = MFMA(w1, a0, acc[0][1]); acc[1][1] = MFMA(w1, a1, acc[1][1]);
        acc[0][2] = MFMA(w2, a0, acc[0][2]); acc[1][2] = MFMA(w2, a1, acc[1][2]);
    };
    auto consume = [&](int fb, const short8* wt0) {
        const unsigned short* fg = &frag[fb];
        short8 a0 = *(const short8*)&fg[lane * 8];
        short8 a1 = *(const short8*)&fg[512 + lane * 8];
#pragma unroll
        for (int kk = 0; kk < 9; kk++) {
            short8 na0, na1;
            if (kk < 8) {
                na0 = *(const short8*)&fg[(kk + 1) * 1024 + lane * 8];
                na1 = *(const short8*)&fg[(kk + 1) * 1024 + 512 + lane * 8];
            }
            short8 w0 = wbuf[kk % 3][0], w1 = wbuf[kk % 3][1], w2 = wbuf[kk % 3][2];
            if (kk < 6) wload(kk % 3, wt0, kk + 3);
            do_mfma(w0, w1, w2, a0, a1);
            if (kk < 8) { a0 = na0; a1 = na1; }
        }
    };
    // body(cc): [post-barrier] raw loads cc+2 -> rbL; weight preload chunk cc;
    //           produce cc+1 from rbP; consume cc; barrier.
    auto body = [&](int cc, const float (&rbP)[4], float (&rbL)[4]) {
#pragma unroll
        for (int i = 0; i < 4; i++) {
            int p = (cc + 2) * 16 + sg * 4 + i;
            p = (p < P_) ? p : (P_ - 1);
            rbL[i] = xb[(size_t)p * C_ + c0 + pr];
        }
        const short8* wt0 = wp + ((size_t)(cc * 9) * NT1 + nt0) * 64 + lane;
        wload(0, wt0, 0); wload(1, wt0, 1); wload(2, wt0, 2);
        produce(((cc + 1) & 1) * FB_, rbP);
        consume((cc & 1) * FB_, wt0);
        __syncthreads();
    };

    float rbA[4], rbB[4];
#pragma unroll
    for (int i = 0; i < 4; i++) {
        rbA[i] = xb[(size_t)(sg * 4 + i) * C_ + c0 + pr];
        rbB[i] = xb[(size_t)(16 + sg * 4 + i) * C_ + c0 + pr];
    }
    produce(0, rbA);            // chunk 0 -> frag[0]
    __syncthreads();

    for (int c2 = 0; c2 < 6; c2++) {          // chunks 0..11
        body(2 * c2,     rbB, rbA);           // produce cc+1 (odd) from rbB
        body(2 * c2 + 1, rbA, rbB);
    }
    // tail: consume chunk 12 (tiles ktl {0,1,8}; weights linear 108..110)
    {
        const short8* wt0 = wp + ((size_t)108 * NT1 + nt0) * 64 + lane;
        wload(0, wt0, 0); wload(1, wt0, 1); wload(2, wt0, 2);
        const unsigned short* fg = &frag[0];  // chunk 12 parity 0
#pragma unroll
        for (int kk = 0; kk < 3; kk++) {
            int ktl = (kk < 2) ? kk : 8;
            short8 a0 = *(const short8*)&fg[ktl * 1024 + lane * 8];
            short8 a1 = *(const short8*)&fg[ktl * 1024 + 512 + lane * 8];
            do_mfma(wbuf[kk][0], wbuf[kk][1], wbuf[kk][2], a0, a1);
        }
    }

    // epilogue: h1t[n][r]
#pragma unroll
    for (int nt = 0; nt < 3; nt++) {
        int n0 = (nt0 + nt) * 32 + 4 * half;
#pragma unroll
        for (int reg = 0; reg < 16; reg++) {
            int n = n0 + (reg & 3) + 8 * (reg >> 2);
            float bv = b1[n];
#pragma unroll
            for (int rt = 0; rt < 2; rt++) {
                h1t[(size_t)n * M_ + blk * 64 + rt * 32 + l31] = f2bf_rne(acc[rt][nt][reg] + bv);
            }
        }
    }
}

// fc2: D[p][r] = W2 * act(h1)^T; out = D + b2 + x.
__global__ __launch_bounds__(256, 2)
void fc2_kernel(const unsigned short* __restrict__ h1t,
                const unsigned short* __restrict__ w2p,
                const float* __restrict__ b2,
                const float* __restrict__ x,
                float* __restrict__ out) {
    __shared__ __align__(16) unsigned short frag[2 * FB_];
    int blk = blockIdx.x;
    int tid = threadIdx.x;
    int rbase = blk * 64;

    int pr  = tid & 63;
    int sg  = tid >> 6;
    int prt = pr >> 5, pl31 = pr & 31;
    int pbase_rbf  = (prt << 9) + pl31 * 8;
    int pbase_silu = 8 * 1024 + (prt << 9) + (((sg >> 1) << 5) | pl31) * 8 + (sg & 1) * 4;

    int wave = sg, lane = tid & 63;
    int l31 = lane & 31, half = lane >> 5;
    int nt0 = wave * 2;
    int ntn = (wave < 3) ? 2 : 1;
    int off1 = (ntn > 1) ? 64 : 0;           // wave 3 dups its tile (discarded)

    f32x16 acc[2][2];
#pragma unroll
    for (int rt = 0; rt < 2; rt++)
#pragma unroll
        for (int nt = 0; nt < 2; nt++)
#pragma unroll
            for (int i = 0; i < 16; i++) acc[rt][nt][i] = 0.f;

    const short8* wp = (const short8*)w2p;
    short8 wbuf[3][2];

    auto wload = [&](int d, const short8* wt0, int kk) {
        const short8* wt = wt0 + (size_t)kk * (NT2 * 64);
        wbuf[d][0] = wt[0]; wbuf[d][1] = wt[off1];
    };
    auto produce = [&](int fb, const unsigned short (&rb)[4]) {
        float v0 = bf2f(rb[0]), v1 = bf2f(rb[1]), v2 = bf2f(rb[2]), v3 = bf2f(rb[3]);
        float vv[4] = {v0, v1, v2, v3};
#pragma unroll
        for (int i = 0; i < 4; i++) {
            int sl = sg * 4 + i;
            *(short8*)&frag[fb + (sl >> 1) * 1024 + ((sl & 1) << 8) + pbase_rbf] = rbf8(vv[i]);
        }
        uint2 sv;
        sv.x = silu2(v0, v1);
        sv.y = silu2(v2, v3);
        *(uint2*)&frag[fb + pbase_silu] = sv;
    };
    auto do_mfma = [&](short8 w0, short8 w1, short8 a0, short8 a1) {
        acc[0][0] = MFMA(w0, a0, acc[0][0]); acc[1][0] = MFMA(w0, a1, acc[1][0]);
        acc[0][1] = MFMA(w1, a0, acc[0][1]); acc[1][1] = MFMA(w1, a1, acc[1][1]);
    };
    auto consume = [&](int fb, const short8* wt0) {
        const unsigned short* fg = &frag[fb];
        short8 a0 = *(const short8*)&fg[lane * 8];
        short8 a1 = *(const short8*)&fg[512 + lane * 8];
#pragma unroll
        for (int kk = 0; kk < 9; kk++) {
            short8 na0, na1;
            if (kk < 8) {
                na0 = *(const short8*)&fg[(kk + 1) * 1024 + lane * 8];
                na1 = *(const short8*)&fg[(kk + 1) * 1024 + 512 + lane * 8];
            }
            short8 w0 = wbuf[kk % 3][0], w1 = wbuf[kk % 3][1];
            if (kk < 6) wload(kk % 3, wt0, kk + 3);
            do_mfma(w0, w1, a0, a1);
            if (kk < 8) { a0 = na0; a1 = na1; }
        }
    };
    auto body = [&](int cc, const unsigned short (&rbP)[4], unsigned short (&rbL)[4]) {
#pragma unroll
        for (int i = 0; i < 4; i++) {
            int s = (cc + 2) * 16 + sg * 4 + i;
            s = (s < HS_) ? s : (HS_ - 1);
            rbL[i] = h1t[(size_t)s * M_ + rbase + pr];
        }
        const short8* wt0 = wp + ((size_t)(cc * 9) * NT2 + nt0) * 64 + lane;
        wload(0, wt0, 0); wload(1, wt0, 1); wload(2, wt0, 2);
        if (cc + 1 < NC2) produce(((cc + 1) & 1) * FB_, rbP);
        consume((cc & 1) * FB_, wt0);
        __syncthreads();
    };

    unsigned short rbA[4], rbB[4];
#pragma unroll
    for (int i = 0; i < 4; i++) {
        rbA[i] = h1t[(size_t)(sg * 4 + i) * M_ + rbase + pr];
        rbB[i] = h1t[(size_t)(16 + sg * 4 + i) * M_ + rbase + pr];
    }
    produce(0, rbA);            // chunk 0 -> frag[0]
    __syncthreads();

    for (int c2 = 0; c2 < 12; c2++) {        // chunks 0..23
        body(2 * c2,     rbB, rbA);
        body(2 * c2 + 1, rbA, rbB);
    }

    // epilogue: out[b,p,c] = acc + b2[p] + x[b,p,c]
    int b = blk / 12;
    int c0 = (blk % 12) * 64;
#pragma unroll
    for (int nt = 0; nt < 2; nt++) {
        if (nt < ntn) {
            int p0 = (nt0 + nt) * 32 + 4 * half;
#pragma unroll
            for (int reg = 0; reg < 16; reg++) {
                int p = p0 + (reg & 3) + 8 * (reg >> 2);
                if (p < P_) {
                    float bv = b2[p];
#pragma unroll
                    for (int rt = 0; rt < 2; rt++) {
                        size_t off = ((size_t)b * P_ + p) * C_ + c0 + rt * 32 + l31;
                        out[off] = acc[rt][nt][reg] + bv + x[off];
                    }
                }
            }
        }
    }
}

extern "C" void kernel_launch(void* const* d_in, const int* in_sizes, int n_in,
                              void* d_out, int out_size, void* d_ws, size_t ws_size,
                              hipStream_t stream) {
    const float* x   = (const float*)d_in[0];
    const float* w1s = (const float*)d_in[1];
    const float* w1b = (const float*)d_in[2];
    const float* b1  = (const float*)d_in[3];
    const float* w2s = (const float*)d_in[4];
    const float* w2b = (const float*)d_in[5];
    const float* b2  = (const float*)d_in[6];
    float* out = (float*)d_out;

    unsigned short* h1t = (unsigned short*)d_ws;            // 37.75 MB bf16 [n][r]
    unsigned short* w1p = h1t + H1_ELEMS;
    unsigned short* w2p = w1p + W1P_ELEMS;                  // total ~40.7 MB

    int pack_blocks = (int)((W1P_ELEMS + W2P_ELEMS) / 256);
    pack_w_kernel<<<pack_blocks, 256, 0, stream>>>(w1s, w1b, w2s, w2b, w1p, w2p);
    fc1_kernel<<<M_ / 64, 256, 0, stream>>>(x, w1p, b1, h1t);
    fc2_kernel<<<M_ / 64, 256, 0, stream>>>(h1t, w2p, b2, x, out);
}